// Round 1
// baseline (474.530 us; speedup 1.0000x reference)
//
#include <hip/hip_runtime.h>
#include <math.h>

#define BB 16
#define NN 8192
#define DD 128
#define CC 64
#define ROWS (BB*NN)            // 131072
#define INV_TEMP (1.0f/6.0f)    // temp = 2*(1+192/96) = 6
#define LDSS 132                // LDS row stride (16B-aligned rows: 132*4=528, 528%16==0)
#define NEGF (-3.402823e38f)

// ---------------------------------------------------------------------------
// Kernel 1: per-row scores -> softmax(q) -> store q -> top4 -> x_common/x_residual
// One row per THREAD (lane-local softmax/topk; no cross-lane ops).
// ---------------------------------------------------------------------------
__global__ __launch_bounds__(256) void k_main(
    const float* __restrict__ x, const float* __restrict__ dict,
    float* __restrict__ xc, float* __restrict__ xr, float* __restrict__ qbuf)
{
    __shared__ __align__(16) float dlds[CC * LDSS];
    const int tid = threadIdx.x;
    for (int idx = tid; idx < CC * DD; idx += 256) {
        dlds[(idx >> 7) * LDSS + (idx & 127)] = dict[idx];
    }
    __syncthreads();

    const int row = blockIdx.x * 256 + tid;
    const float* xrow = x + (size_t)row * DD;

    // ---- scores: s[c] = dot(x_row, dict[c]) ; dict operand is wave-uniform
    float s[CC];
#pragma unroll
    for (int c = 0; c < CC; ++c) s[c] = 0.f;

    for (int j = 0; j < DD; j += 4) {
        const float4 xv = *(const float4*)(xrow + j);
#pragma unroll
        for (int c = 0; c < CC; ++c) {
            const float* dp = dict + c * DD + j;   // uniform address -> s_load
            float acc = s[c];
            acc = fmaf(xv.x, dp[0], acc);
            acc = fmaf(xv.y, dp[1], acc);
            acc = fmaf(xv.z, dp[2], acc);
            acc = fmaf(xv.w, dp[3], acc);
            s[c] = acc;
        }
    }

    // ---- softmax over C at temp 6 (matches log_softmax(scores/temp))
    float m = s[0];
#pragma unroll
    for (int c = 1; c < CC; ++c) m = fmaxf(m, s[c]);
    float Z = 0.f;
#pragma unroll
    for (int c = 0; c < CC; ++c) Z += __expf((s[c] - m) * INV_TEMP);
    const float rZ = 1.f / Z;

    // ---- store q row (needed by the global colsum + KL passes)
    float* qrow = qbuf + (size_t)row * CC;
#pragma unroll
    for (int c = 0; c < CC; c += 4) {
        float4 qv;
        qv.x = __expf((s[c + 0] - m) * INV_TEMP) * rZ;
        qv.y = __expf((s[c + 1] - m) * INV_TEMP) * rZ;
        qv.z = __expf((s[c + 2] - m) * INV_TEMP) * rZ;
        qv.w = __expf((s[c + 3] - m) * INV_TEMP) * rZ;
        *(float4*)(qrow + c) = qv;
    }

    // ---- top-4 (strict '>' => lowest index on ties, matches lax.top_k)
    float tv0, tv1, tv2, tv3;
    int   ti0, ti1, ti2, ti3;
    {
        float best = NEGF; int bi = 0;
#pragma unroll
        for (int c = 0; c < CC; ++c) { if (s[c] > best) { best = s[c]; bi = c; } }
        tv0 = best; ti0 = bi;
    }
    {
        float best = NEGF; int bi = 0;
#pragma unroll
        for (int c = 0; c < CC; ++c) {
            float v = (c == ti0) ? NEGF : s[c];
            if (v > best) { best = v; bi = c; }
        }
        tv1 = best; ti1 = bi;
    }
    {
        float best = NEGF; int bi = 0;
#pragma unroll
        for (int c = 0; c < CC; ++c) {
            float v = (c == ti0 || c == ti1) ? NEGF : s[c];
            if (v > best) { best = v; bi = c; }
        }
        tv2 = best; ti2 = bi;
    }
    {
        float best = NEGF; int bi = 0;
#pragma unroll
        for (int c = 0; c < CC; ++c) {
            float v = (c == ti0 || c == ti1 || c == ti2) ? NEGF : s[c];
            if (v > best) { best = v; bi = c; }
        }
        tv3 = best; ti3 = bi;
    }

    // ---- softmax over the 4 selected scores
    const float e1 = __expf((tv1 - tv0) * INV_TEMP);
    const float e2 = __expf((tv2 - tv0) * INV_TEMP);
    const float e3 = __expf((tv3 - tv0) * INV_TEMP);
    const float rZ4 = 1.f / (1.f + e1 + e2 + e3);
    const float w0 = rZ4, w1 = e1 * rZ4, w2 = e2 * rZ4, w3 = e3 * rZ4;

    // ---- x_common = sum_k wk * dict[tik] ; x_residual = x - x_common
    float* xcrow = xc + (size_t)row * DD;
    float* xrrow = xr + (size_t)row * DD;
    const float* d0 = &dlds[ti0 * LDSS];
    const float* d1 = &dlds[ti1 * LDSS];
    const float* d2 = &dlds[ti2 * LDSS];
    const float* d3 = &dlds[ti3 * LDSS];
#pragma unroll 4
    for (int j = 0; j < DD; j += 4) {
        const float4 a  = *(const float4*)(d0 + j);
        const float4 b  = *(const float4*)(d1 + j);
        const float4 c2 = *(const float4*)(d2 + j);
        const float4 d4 = *(const float4*)(d3 + j);
        float4 com;
        com.x = fmaf(w3, d4.x, fmaf(w2, c2.x, fmaf(w1, b.x, w0 * a.x)));
        com.y = fmaf(w3, d4.y, fmaf(w2, c2.y, fmaf(w1, b.y, w0 * a.y)));
        com.z = fmaf(w3, d4.z, fmaf(w2, c2.z, fmaf(w1, b.z, w0 * a.z)));
        com.w = fmaf(w3, d4.w, fmaf(w2, c2.w, fmaf(w1, b.w, w0 * a.w)));
        const float4 xv = *(const float4*)(xrow + j);
        float4 res;
        res.x = xv.x - com.x; res.y = xv.y - com.y;
        res.z = xv.z - com.z; res.w = xv.w - com.w;
        *(float4*)(xcrow + j) = com;
        *(float4*)(xrrow + j) = res;
    }
}

// ---------------------------------------------------------------------------
// Kernel 2: colsum[c] = sum over all rows of q[row][c]  (coalesced grid-stride)
// ---------------------------------------------------------------------------
__global__ __launch_bounds__(256) void k_colsum(
    const float* __restrict__ qbuf, float* __restrict__ colsum)
{
    __shared__ float part[CC];
    const int tid = threadIdx.x;
    if (tid < CC) part[tid] = 0.f;
    __syncthreads();
    const size_t total  = (size_t)ROWS * CC;
    const size_t stride = (size_t)gridDim.x * 256;   // multiple of 64 -> fixed c per thread
    float local = 0.f;
    for (size_t i = (size_t)blockIdx.x * 256 + tid; i < total; i += stride)
        local += qbuf[i];
    atomicAdd(&part[tid & 63], local);
    __syncthreads();
    if (tid < CC) atomicAdd(&colsum[tid], part[tid]);
}

// ---------------------------------------------------------------------------
// Kernel 3: KL contribution per row. log p - log q = log q - log F_c - log S_row
// ---------------------------------------------------------------------------
__global__ __launch_bounds__(256) void k_kl(
    const float* __restrict__ qbuf, const float* __restrict__ colsum,
    float* __restrict__ klacc)
{
    __shared__ float rF[CC], lF[CC];
    const int tid = threadIdx.x;
    if (tid < CC) {
        const float F = colsum[tid];
        rF[tid] = 1.f / F;
        lF[tid] = __logf(F);
    }
    __syncthreads();

    const int row = blockIdx.x * 256 + tid;
    const float* qrow = qbuf + (size_t)row * CC;
    float q[CC];
#pragma unroll
    for (int c = 0; c < CC; c += 4) {
        const float4 v = *(const float4*)(qrow + c);
        q[c] = v.x; q[c + 1] = v.y; q[c + 2] = v.z; q[c + 3] = v.w;
    }
    float S = 0.f;
#pragma unroll
    for (int c = 0; c < CC; ++c) S += q[c] * q[c] * rF[c];
    const float rS = 1.f / S;
    const float lS = __logf(S);

    float contrib = 0.f;
#pragma unroll
    for (int c = 0; c < CC; ++c) {
        const float wv = q[c] * q[c] * rF[c];
        const float lq = __logf(q[c]);
        contrib += (wv * rS) * (lq - lF[c] - lS);
    }
    // wave reduce, one atomic per wave
#pragma unroll
    for (int off = 32; off > 0; off >>= 1)
        contrib += __shfl_down(contrib, off, 64);
    if ((tid & 63) == 0) atomicAdd(klacc, contrib);
}

// ---------------------------------------------------------------------------
// Kernel 4: ortho accumulator = sum over (i,j) of (gram[i][j]-I)^2
// ---------------------------------------------------------------------------
__global__ __launch_bounds__(256) void k_ortho(
    const float* __restrict__ dict, float* __restrict__ oacc)
{
    __shared__ __align__(16) float dlds[CC * LDSS];
    const int tid = threadIdx.x;
    for (int idx = tid; idx < CC * DD; idx += 256)
        dlds[(idx >> 7) * LDSS + (idx & 127)] = dict[idx];
    __syncthreads();

    const int e = blockIdx.x * 256 + tid;   // grid 16 -> e in [0,4096)
    const int i = e >> 6, jj = e & 63;
    const float* di = &dlds[i * LDSS];
    const float* dj = &dlds[jj * LDSS];
    float g = 0.f;
#pragma unroll 8
    for (int d = 0; d < DD; d += 4) {
        const float4 a = *(const float4*)(di + d);
        const float4 b = *(const float4*)(dj + d);
        g += a.x * b.x + a.y * b.y + a.z * b.z + a.w * b.w;
    }
    const float diff = g - ((i == jj) ? 1.f : 0.f);
    float v = diff * diff;
#pragma unroll
    for (int off = 32; off > 0; off >>= 1)
        v += __shfl_down(v, off, 64);
    if ((tid & 63) == 0) atomicAdd(oacc, v);
}

// ---------------------------------------------------------------------------
// Kernel 5: aux = 0.5 * kl/(B*N) + 0.1 * ortho/4096
// ---------------------------------------------------------------------------
__global__ void k_final(const float* __restrict__ klacc,
                        const float* __restrict__ oacc,
                        float* __restrict__ out_scalar)
{
    out_scalar[0] = 0.5f * (klacc[0] / (float)ROWS) + 0.1f * (oacc[0] / 4096.f);
}

// ---------------------------------------------------------------------------
extern "C" void kernel_launch(void* const* d_in, const int* in_sizes, int n_in,
                              void* d_out, int out_size, void* d_ws, size_t ws_size,
                              hipStream_t stream)
{
    const float* x    = (const float*)d_in[0];   // (16, 8192, 128)
    const float* dict = (const float*)d_in[1];   // (64, 128)
    float* out = (float*)d_out;
    float* xc  = out;                               // (B,N,D)
    float* xr  = out + (size_t)ROWS * DD;           // (B,N,D)
    float* aux = out + 2 * (size_t)ROWS * DD;       // scalar

    float* ws     = (float*)d_ws;
    float* colsum = ws;           // 64 floats
    float* klacc  = ws + 64;      // 1 float
    float* oacc   = ws + 65;      // 1 float
    float* qbuf   = ws + 256;     // 131072*64 floats = 33.5 MB, 1KB-aligned

    hipMemsetAsync(d_ws, 0, 1024, stream);

    k_main  <<<ROWS / 256, 256, 0, stream>>>(x, dict, xc, xr, qbuf);
    k_colsum<<<1024,       256, 0, stream>>>(qbuf, colsum);
    k_kl    <<<ROWS / 256, 256, 0, stream>>>(qbuf, colsum, klacc);
    k_ortho <<<16,         256, 0, stream>>>(dict, oacc);
    k_final <<<1,          1,   0, stream>>>(klacc, oacc, aux);
}

// Round 2
// 369.843 us; speedup vs baseline: 1.2831x; 1.2831x over previous
//
#include <hip/hip_runtime.h>
#include <math.h>

#define BB 16
#define NN 8192
#define DD 128
#define CC 64
#define ROWS (BB*NN)            // 131072
#define INV_TEMP (1.0f/6.0f)    // temp = 2*(1+192/96) = 6
#define NEGF (-3.402823e38f)
#define LDSS 132                // k_ortho LDS row stride

#define RPB 128                 // rows per block in k_main
#define CHW 32                  // chunk width (floats of j)
#define XST 34                  // LDS row stride in dwords (2-way conflict max, 8B aligned)

__device__ __forceinline__ unsigned f2bf(float f) {
    unsigned u = __builtin_bit_cast(unsigned, f);
    return (u + 0x7fffu + ((u >> 16) & 1u)) >> 16;   // RNE
}
__device__ __forceinline__ float bflo(unsigned u) { return __builtin_bit_cast(float, u << 16); }
__device__ __forceinline__ float bfhi(unsigned u) { return __builtin_bit_cast(float, u & 0xffff0000u); }

// ---------------------------------------------------------------------------
// k_main: 2 threads per row (c-halves). Waves 0-1: c 0..31 for rows 0..127;
// waves 2-3: c 32..63. All global x/q/xc/xr traffic staged through LDS for
// coalescing. Dict for the score FMA loop via wave-uniform s_load; dict for
// the top-4 combine gathered from global (32 KB, L1-resident).
// ---------------------------------------------------------------------------
__global__ __launch_bounds__(256, 4) void k_main(
    const float* __restrict__ x, const float* __restrict__ dict,
    float* __restrict__ xcg, float* __restrict__ xrg,
    unsigned* __restrict__ qg, float* __restrict__ colpart)
{
    __shared__ __align__(16) float bufA[RPB * XST];   // 17408 B
    __shared__ __align__(16) float bufB[RPB * XST];   // 17408 B (t4 exchange, q staging, xc staging)
    __shared__ float red2[RPB][2];
    __shared__ float colsumA[CC];

    const int tid   = threadIdx.x;
    const int rloc  = tid & (RPB - 1);
    const int chalf = tid >> 7;
    const int cbase = __builtin_amdgcn_readfirstlane(chalf << 5);  // wave-uniform -> s_load
    const int row0  = blockIdx.x * RPB;

    if (tid < CC) colsumA[tid] = 0.f;

    float s[32];
#pragma unroll
    for (int cc = 0; cc < 32; ++cc) s[cc] = 0.f;

    // ---------------- phase 1: scores over 4 staged chunks ----------------
    for (int ch = 0; ch < 4; ++ch) {
        const int j0 = ch * CHW;
        __syncthreads();   // prev consumers of bufA done
#pragma unroll
        for (int p = 0; p < 4; ++p) {
            const int r  = (tid >> 3) + 32 * p;
            const int jg = (tid & 7) * 4;
            const float4 v = *(const float4*)(x + (size_t)(row0 + r) * DD + j0 + jg);
            float* dst = &bufA[XST * r + jg];
            *(float2*)dst       = make_float2(v.x, v.y);
            *(float2*)(dst + 2) = make_float2(v.z, v.w);
        }
        __syncthreads();
        const float* xrow = &bufA[XST * rloc];
        for (int js = 0; js < CHW; js += 4) {
            const float2 x01 = *(const float2*)(xrow + js);
            const float2 x23 = *(const float2*)(xrow + js + 2);
            const float* dcol = dict + (size_t)cbase * DD + (j0 + js);
#pragma unroll
            for (int cc = 0; cc < 32; ++cc) {
                const float* dp = dcol + cc * DD;   // uniform address -> s_load
                float acc = s[cc];
                acc = fmaf(x01.x, dp[0], acc);
                acc = fmaf(x01.y, dp[1], acc);
                acc = fmaf(x23.x, dp[2], acc);
                acc = fmaf(x23.y, dp[3], acc);
                s[cc] = acc;
            }
        }
    }

    // ---------------- phase 2: softmax across the pair ----------------
    float lm = s[0];
#pragma unroll
    for (int cc = 1; cc < 32; ++cc) lm = fmaxf(lm, s[cc]);
    red2[rloc][chalf] = lm;
    __syncthreads();
    const float mg = fmaxf(red2[rloc][0], red2[rloc][1]);
    __syncthreads();
    float lz = 0.f;
#pragma unroll
    for (int cc = 0; cc < 32; ++cc) lz += __expf((s[cc] - mg) * INV_TEMP);
    red2[rloc][chalf] = lz;
    __syncthreads();
    const float rZ = 1.f / (red2[rloc][0] + red2[rloc][1]);

    // ---------------- top-4 local (strict '>' => lowest index on ties) ----
    float tv[4]; int ti[4];
    {
        float best = NEGF; int bi = 0;
#pragma unroll
        for (int cc = 0; cc < 32; ++cc) { if (s[cc] > best) { best = s[cc]; bi = cc; } }
        tv[0] = best; ti[0] = bi;
    }
    {
        float best = NEGF; int bi = 0;
#pragma unroll
        for (int cc = 0; cc < 32; ++cc) {
            const float v = (cc == ti[0]) ? NEGF : s[cc];
            if (v > best) { best = v; bi = cc; }
        }
        tv[1] = best; ti[1] = bi;
    }
    {
        float best = NEGF; int bi = 0;
#pragma unroll
        for (int cc = 0; cc < 32; ++cc) {
            const float v = (cc == ti[0] || cc == ti[1]) ? NEGF : s[cc];
            if (v > best) { best = v; bi = cc; }
        }
        tv[2] = best; ti[2] = bi;
    }
    {
        float best = NEGF; int bi = 0;
#pragma unroll
        for (int cc = 0; cc < 32; ++cc) {
            const float v = (cc == ti[0] || cc == ti[1] || cc == ti[2]) ? NEGF : s[cc];
            if (v > best) { best = v; bi = cc; }
        }
        tv[3] = best; ti[3] = bi;
    }

    // ---------------- s -> q in place (s dead after top-4 extraction) -----
#pragma unroll
    for (int cc = 0; cc < 32; ++cc) s[cc] = __expf((s[cc] - mg) * INV_TEMP) * rZ;

    // fused column-sum partials
#pragma unroll
    for (int cc = 0; cc < 32; ++cc) atomicAdd(&colsumA[cbase + cc], s[cc]);

    // ---------------- top-4 merge across the pair (via LDS) ---------------
    float* t4v = bufB;
    int*   t4i = (int*)(bufB + 1024);
    {
        const int b4 = (rloc * 2 + chalf) * 4;
#pragma unroll
        for (int k = 0; k < 4; ++k) { t4v[b4 + k] = tv[k]; t4i[b4 + k] = cbase + ti[k]; }
    }
    __syncthreads();
    float cv[8]; int ci[8];
#pragma unroll
    for (int h = 0; h < 2; ++h) {
#pragma unroll
        for (int k = 0; k < 4; ++k) {
            cv[h * 4 + k] = t4v[(rloc * 2 + h) * 4 + k];
            ci[h * 4 + k] = t4i[(rloc * 2 + h) * 4 + k];
        }
    }
    __syncthreads();   // bufB free for reuse after this

    // ranks over 8 candidates (total order: value desc, index asc on ties)
    int rank[8];
#pragma unroll
    for (int j = 0; j < 8; ++j) rank[j] = 0;
#pragma unroll
    for (int j = 0; j < 8; ++j) {
#pragma unroll
        for (int k = 0; k < 8; ++k) {
            if (k == j) continue;
            const bool kg = (cv[k] > cv[j]) || (cv[k] == cv[j] && ci[k] < ci[j]);
            rank[j] += kg ? 1 : 0;
        }
    }
    float sv[4]; int si[4];
#pragma unroll
    for (int t2 = 0; t2 < 4; ++t2) { sv[t2] = NEGF; si[t2] = 0; }
#pragma unroll
    for (int j = 0; j < 8; ++j) {
#pragma unroll
        for (int t2 = 0; t2 < 4; ++t2) {
            const bool sel = (rank[j] == t2);
            sv[t2] = sel ? cv[j] : sv[t2];
            si[t2] = sel ? ci[j] : si[t2];
        }
    }
    // softmax over the 4 selected scores (order-invariant for the combine)
    const float e1 = __expf((sv[1] - sv[0]) * INV_TEMP);
    const float e2 = __expf((sv[2] - sv[0]) * INV_TEMP);
    const float e3 = __expf((sv[3] - sv[0]) * INV_TEMP);
    const float rZ4 = 1.f / (1.f + e1 + e2 + e3);
    const float w0 = rZ4, w1 = e1 * rZ4, w2 = e2 * rZ4, w3 = e3 * rZ4;

    // ---------------- q -> LDS (bf16) -> coalesced global store -----------
    {
        unsigned* qs = (unsigned*)bufB;
        const int base = XST * rloc + 16 * chalf;
#pragma unroll
        for (int k2 = 0; k2 < 16; k2 += 2) {
            uint2 w;
            w.x = (f2bf(s[2 * k2 + 1]) << 16) | f2bf(s[2 * k2 + 0]);
            w.y = (f2bf(s[2 * k2 + 3]) << 16) | f2bf(s[2 * k2 + 2]);
            *(uint2*)&qs[base + k2] = w;
        }
        __syncthreads();
        unsigned* qdst = qg + (size_t)blockIdx.x * (RPB * 32);
#pragma unroll
        for (int k4 = 0; k4 < 4; ++k4) {
            const int gd  = k4 * 1024 + tid * 4;
            const int row = gd >> 5, kk = gd & 31;
            const uint2 a = *(const uint2*)&qs[XST * row + kk];
            const uint2 b = *(const uint2*)&qs[XST * row + kk + 2];
            uint4 o; o.x = a.x; o.y = a.y; o.z = b.x; o.w = b.y;
            *(uint4*)&qdst[gd] = o;
        }
    }

    // ---------------- phase 3: x_common / x_residual, staged -------------
    for (int ch = 0; ch < 4; ++ch) {
        const int j0 = ch * CHW;
        __syncthreads();   // prev readers of bufA/bufB done
#pragma unroll
        for (int p = 0; p < 4; ++p) {
            const int r  = (tid >> 3) + 32 * p;
            const int jg = (tid & 7) * 4;
            const float4 v = *(const float4*)(x + (size_t)(row0 + r) * DD + j0 + jg);
            float* dst = &bufA[XST * r + jg];
            *(float2*)dst       = make_float2(v.x, v.y);
            *(float2*)(dst + 2) = make_float2(v.z, v.w);
        }
        __syncthreads();
        {
            float* xcb = &bufB[XST * rloc];
#pragma unroll
            for (int g = 0; g < 4; ++g) {
                const int jj = 8 * g + 4 * chalf;
                const float4 d0 = *(const float4*)(dict + (size_t)si[0] * DD + j0 + jj);
                const float4 d1 = *(const float4*)(dict + (size_t)si[1] * DD + j0 + jj);
                const float4 d2 = *(const float4*)(dict + (size_t)si[2] * DD + j0 + jj);
                const float4 d3 = *(const float4*)(dict + (size_t)si[3] * DD + j0 + jj);
                float4 c;
                c.x = fmaf(w3, d3.x, fmaf(w2, d2.x, fmaf(w1, d1.x, w0 * d0.x)));
                c.y = fmaf(w3, d3.y, fmaf(w2, d2.y, fmaf(w1, d1.y, w0 * d0.y)));
                c.z = fmaf(w3, d3.z, fmaf(w2, d2.z, fmaf(w1, d1.z, w0 * d0.z)));
                c.w = fmaf(w3, d3.w, fmaf(w2, d2.w, fmaf(w1, d1.w, w0 * d0.w)));
                *(float2*)&xcb[jj]     = make_float2(c.x, c.y);
                *(float2*)&xcb[jj + 2] = make_float2(c.z, c.w);
            }
        }
        __syncthreads();
#pragma unroll
        for (int k4 = 0; k4 < 4; ++k4) {
            const int gd  = k4 * 1024 + tid * 4;
            const int row = gd >> 5, kk = gd & 31;
            const float2 xa = *(const float2*)&bufA[XST * row + kk];
            const float2 xb = *(const float2*)&bufA[XST * row + kk + 2];
            const float2 ca = *(const float2*)&bufB[XST * row + kk];
            const float2 cb = *(const float2*)&bufB[XST * row + kk + 2];
            float4 c4; c4.x = ca.x; c4.y = ca.y; c4.z = cb.x; c4.w = cb.y;
            float4 r4; r4.x = xa.x - c4.x; r4.y = xa.y - c4.y;
            r4.z = xb.x - c4.z; r4.w = xb.y - c4.w;
            const size_t go = (size_t)(row0 + row) * DD + j0 + kk;
            *(float4*)(xcg + go) = c4;
            *(float4*)(xrg + go) = r4;
        }
    }

    __syncthreads();
    if (tid < CC) colpart[blockIdx.x * CC + tid] = colsumA[tid];
}

// ---------------------------------------------------------------------------
// k_colsum: reduce colpart[1024][64] -> colsum[64]
// ---------------------------------------------------------------------------
__global__ void k_colsum(const float* __restrict__ colpart, float* __restrict__ colsum)
{
    const int tid = threadIdx.x;                     // grid 16 x 256
    const int c   = tid & 63;
    const int seg = blockIdx.x * 4 + (tid >> 6);     // 0..63
    float v = 0.f;
#pragma unroll
    for (int b = 0; b < 16; ++b)
        v += colpart[(seg * 16 + b) * 64 + c];
    atomicAdd(&colsum[c], v);
}

// ---------------------------------------------------------------------------
// k_kl: per-row KL from bf16 q (LDS-staged coalesced reads)
// log p - log q = log q - log F_c - log S_row
// ---------------------------------------------------------------------------
__global__ __launch_bounds__(256, 2) void k_kl(
    const unsigned* __restrict__ qg, const float* __restrict__ colsum,
    float* __restrict__ klacc)
{
    __shared__ __align__(8) unsigned qs[256 * XST];  // 34816 B
    __shared__ float rF[CC], lF[CC];
    const int tid = threadIdx.x;
    if (tid < CC) { const float F = colsum[tid]; rF[tid] = 1.f / F; lF[tid] = __logf(F); }
    const unsigned* qb = qg + (size_t)blockIdx.x * 8192;
#pragma unroll
    for (int g = 0; g < 8; ++g) {
        const int gd = g * 1024 + tid * 4;
        const uint4 v = *(const uint4*)(qb + gd);
        const int row = gd >> 5, kk = gd & 31;
        *(uint2*)&qs[XST * row + kk]     = make_uint2(v.x, v.y);
        *(uint2*)&qs[XST * row + kk + 2] = make_uint2(v.z, v.w);
    }
    __syncthreads();
    const unsigned* qr = &qs[XST * tid];
    unsigned u[32];
#pragma unroll
    for (int k = 0; k < 32; k += 2) {
        const uint2 t2 = *(const uint2*)&qr[k];
        u[k] = t2.x; u[k + 1] = t2.y;
    }
    float S = 0.f;
#pragma unroll
    for (int k = 0; k < 32; ++k) {
        const float f0 = bflo(u[k]), f1 = bfhi(u[k]);
        S = fmaf(f0 * f0, rF[2 * k], S);
        S = fmaf(f1 * f1, rF[2 * k + 1], S);
    }
    const float rS = 1.f / S;
    const float lS = __logf(S);
    float acc = 0.f;
#pragma unroll
    for (int k = 0; k < 32; ++k) {
        const float f0 = bflo(u[k]), f1 = bfhi(u[k]);
        const float p0 = f0 * f0 * rF[2 * k] * rS;
        const float p1 = f1 * f1 * rF[2 * k + 1] * rS;
        acc += p0 * (__logf(f0) - lF[2 * k] - lS);
        acc += p1 * (__logf(f1) - lF[2 * k + 1] - lS);
    }
#pragma unroll
    for (int off = 32; off > 0; off >>= 1) acc += __shfl_down(acc, off, 64);
    if ((tid & 63) == 0) atomicAdd(klacc, acc);
}

// ---------------------------------------------------------------------------
// k_ortho: sum over (i,j) of (gram[i][j]-I)^2
// ---------------------------------------------------------------------------
__global__ __launch_bounds__(256) void k_ortho(
    const float* __restrict__ dict, float* __restrict__ oacc)
{
    __shared__ __align__(16) float dlds[CC * LDSS];
    const int tid = threadIdx.x;
    for (int idx = tid; idx < CC * DD; idx += 256)
        dlds[(idx >> 7) * LDSS + (idx & 127)] = dict[idx];
    __syncthreads();

    const int e = blockIdx.x * 256 + tid;   // grid 16 -> e in [0,4096)
    const int i = e >> 6, jj = e & 63;
    const float* di = &dlds[i * LDSS];
    const float* dj = &dlds[jj * LDSS];
    float g = 0.f;
#pragma unroll 8
    for (int d = 0; d < DD; d += 4) {
        const float4 a = *(const float4*)(di + d);
        const float4 b = *(const float4*)(dj + d);
        g += a.x * b.x + a.y * b.y + a.z * b.z + a.w * b.w;
    }
    const float diff = g - ((i == jj) ? 1.f : 0.f);
    float v = diff * diff;
#pragma unroll
    for (int off = 32; off > 0; off >>= 1)
        v += __shfl_down(v, off, 64);
    if ((tid & 63) == 0) atomicAdd(oacc, v);
}

// ---------------------------------------------------------------------------
__global__ void k_final(const float* __restrict__ klacc,
                        const float* __restrict__ oacc,
                        float* __restrict__ out_scalar)
{
    out_scalar[0] = 0.5f * (klacc[0] / (float)ROWS) + 0.1f * (oacc[0] / 4096.f);
}

// ---------------------------------------------------------------------------
extern "C" void kernel_launch(void* const* d_in, const int* in_sizes, int n_in,
                              void* d_out, int out_size, void* d_ws, size_t ws_size,
                              hipStream_t stream)
{
    const float* x    = (const float*)d_in[0];   // (16, 8192, 128)
    const float* dict = (const float*)d_in[1];   // (64, 128)
    float* out = (float*)d_out;
    float* xcg = out;                               // (B,N,D)
    float* xrg = out + (size_t)ROWS * DD;           // (B,N,D)
    float* aux = out + 2 * (size_t)ROWS * DD;       // scalar

    float* ws      = (float*)d_ws;
    float* colsum  = ws;                 // 64 floats
    float* klacc   = ws + 64;            // 1
    float* oacc    = ws + 65;            // 1
    float* colpart = ws + 256;           // 1024*64 floats = 256 KB
    unsigned* qbuf = (unsigned*)(ws + 256 + 1024 * 64);  // 131072*32 dwords = 16.75 MB

    hipMemsetAsync(d_ws, 0, 1024, stream);

    k_main  <<<ROWS / RPB, 256, 0, stream>>>(x, dict, xcg, xrg, qbuf, colpart);
    k_colsum<<<16,         256, 0, stream>>>(colpart, colsum);
    k_kl    <<<ROWS / 256, 256, 0, stream>>>(qbuf, colsum, klacc);
    k_ortho <<<16,         256, 0, stream>>>(dict, oacc);
    k_final <<<1,          1,   0, stream>>>(klacc, oacc, aux);
}